// Round 9
// baseline (334.472 us; speedup 1.0000x reference)
//
#include <hip/hip_runtime.h>
#include <stdint.h>

#define B_ 4
#define L_ 4096
#define H_ 8
#define D_ 64
#define S_ 45
#define U_ 45
#define BH_ 32
#define KC_ 16                     // split-k chunks (256 keys each)
#define STRIDE_ (H_*D_)            // 512 floats between consecutive l
#define BSTR_ ((size_t)L_*H_*D_)   // 2097152 floats per batch

// index_sample declared int64 in the reference; harness may pass int32 or int64.
__device__ __forceinline__ bool detect_idx64(const int* idxp){
    bool z = true;
    #pragma unroll
    for (int i = 1; i < 32; i += 2) z = z && (idxp[i] == 0);
    return z;
}

// Nontemporal float4 load/store (HIP float4 is a struct; go through ext_vector).
typedef float v4f_ __attribute__((ext_vector_type(4)));
__device__ __forceinline__ float4 ntload4(const float4* p){
    v4f_ v = __builtin_nontemporal_load((const v4f_*)p);
    return make_float4(v.x, v.y, v.z, v.w);
}
__device__ __forceinline__ void ntstore4(float4* p, float4 f){
    v4f_ v; v.x = f.x; v.y = f.y; v.z = f.z; v.w = f.w;
    __builtin_nontemporal_store(v, (v4f_*)p);
}

// ---------- kernel A: M[bh][q] = max_s(dot) - sum_s(dot)/L ----------
// 4-head-fused gather (ROUND-4 BEST): one sample row = K[b, ki, hg*4..+3, :]
// = 1 KB contiguous. One (b,hg) per XCD via g&7 -> 4.0 MB hot K slice == L2
// size (8-head/8 MB thrashes: FETCH 46->393 MB, 77->117 us). 77 us =
// 2.45 TB/s/XCD = ~57% per-XCD L2 service rate. NT hints on read-once traffic.
__global__ __launch_bounds__(256) void kM(const float* __restrict__ Qb,
                                          const float* __restrict__ Kb,
                                          const int* __restrict__ idxp,
                                          float* __restrict__ Mout){
    int g = blockIdx.x;                 // 0..2047
    int grp8 = g & 7;                   // one (b, head-half) per XCD
    int b  = grp8 >> 1;
    int hg = grp8 & 1;
    int chunk = g >> 3;                 // 0..255
    int q0 = chunk * 16;
    bool idx64 = detect_idx64(idxp);

    __shared__ int lidx[16*S_];         // 2.88 KB: this block's 16 q x 45 idx
    for (int i = threadIdx.x; i < 16*S_; i += 256)
        lidx[i] = idx64 ? __builtin_nontemporal_load(&idxp[2*(q0*S_ + i)])
                        : __builtin_nontemporal_load(&idxp[q0*S_ + i]);
    __syncthreads();

    int lane = threadIdx.x & 63;
    int w    = threadIdx.x >> 6;        // wave 0..3
    int grp  = lane >> 4;               // 16-lane group: one q each
    int l16  = lane & 15;
    int ql   = w*4 + grp;               // 0..15
    int q    = q0 + ql;

    const float4* qr = (const float4*)(Qb + (size_t)b*BSTR_ + (size_t)q*STRIDE_ + hg*256);
    float4 qf0 = ntload4(qr + l16);        // head hg*4+0, dims l16*4..+3
    float4 qf1 = ntload4(qr + 16 + l16);   // head hg*4+1
    float4 qf2 = ntload4(qr + 32 + l16);   // head hg*4+2
    float4 qf3 = ntload4(qr + 48 + l16);   // head hg*4+3

    const float* kbase = Kb + (size_t)b*BSTR_ + hg*256;
    // lane<8 of each group accumulates heads {0,1}; lane>=8 heads {2,3}
    float mxa = -1e30f, mxb = -1e30f, sma = 0.f, smb = 0.f;
    const int* myIdx = &lidx[ql*S_];

    #pragma unroll 3
    for (int s = 0; s < S_; s++){
        int ki = myIdx[s];              // broadcast within group
        const float4* kr = (const float4*)(kbase + (size_t)ki*STRIDE_);
        float4 k0 = kr[l16], k1 = kr[16+l16], k2 = kr[32+l16], k3 = kr[48+l16];
        float p0 = qf0.x*k0.x; p0 = fmaf(qf0.y,k0.y,p0); p0 = fmaf(qf0.z,k0.z,p0); p0 = fmaf(qf0.w,k0.w,p0);
        float p1 = qf1.x*k1.x; p1 = fmaf(qf1.y,k1.y,p1); p1 = fmaf(qf1.z,k1.z,p1); p1 = fmaf(qf1.w,k1.w,p1);
        float p2 = qf2.x*k2.x; p2 = fmaf(qf2.y,k2.y,p2); p2 = fmaf(qf2.z,k2.z,p2); p2 = fmaf(qf2.w,k2.w,p2);
        float p3 = qf3.x*k3.x; p3 = fmaf(qf3.y,k3.y,p3); p3 = fmaf(qf3.z,k3.z,p3); p3 = fmaf(qf3.w,k3.w,p3);
        // fold the two 8-lane halves of each head partial (1 shfl each)
        float u0 = p0 + __shfl_xor(p0, 8);
        float u1 = p1 + __shfl_xor(p1, 8);
        float u2 = p2 + __shfl_xor(p2, 8);
        float u3 = p3 + __shfl_xor(p3, 8);
        // lane specialization: low half carries heads 0/1, high half 2/3
        float va = (l16 < 8) ? u0 : u2;
        float vb = (l16 < 8) ? u1 : u3;
        #pragma unroll
        for (int off = 1; off < 8; off <<= 1){
            va += __shfl_xor(va, off);
            vb += __shfl_xor(vb, off);
        }
        mxa = fmaxf(mxa, va); sma += va;
        mxb = fmaxf(mxb, vb); smb += vb;
    }
    // writers: l16==0 -> head0(a), l16==1 -> head1(b), l16==8 -> head2(a), l16==9 -> head3(b)
    int hsel = (l16==0) ? 0 : (l16==1) ? 1 : (l16==8) ? 2 : (l16==9) ? 3 : -1;
    if (hsel >= 0){
        float mv = (l16 & 1) ? mxb : mxa;
        float sv = (l16 & 1) ? smb : sma;
        __builtin_nontemporal_store(mv - sv*(1.0f/L_),
            &Mout[(size_t)(b*8 + hg*4 + hsel)*L_ + q]);
    }
}

// ---------- fused top-45 per (b,h) + mean zero (selRow eliminated, R8) ----------
__global__ __launch_bounds__(512) void kTopF(const float* __restrict__ M,
                                             int* __restrict__ Mtop,
                                             float* __restrict__ meanZ){
    int bh = blockIdx.x;
    int t = threadIdx.x;
    if (t < 64) meanZ[bh*64 + t] = 0.f;

    __shared__ float cV[8*U_];
    __shared__ int   cI[8*U_];
    int wv = t >> 6, lane = t & 63;      // wv = segment 0..7
    const float* Mr = M + (size_t)bh*L_ + wv*512;
    float v[8];
    #pragma unroll
    for (int j = 0; j < 8; j++) v[j] = Mr[lane + 64*j];

    for (int it = 0; it < U_; it++){
        float best = -1e30f; int bidx = 0x7fffffff;
        #pragma unroll
        for (int j = 0; j < 8; j++){
            int id = lane + 64*j;
            if (v[j] > best){ best = v[j]; bidx = id; }   // ascending id scan
        }
        #pragma unroll
        for (int off = 1; off < 64; off <<= 1){
            float ov = __shfl_xor(best, off); int oi = __shfl_xor(bidx, off);
            if (ov > best || (ov == best && oi < bidx)){ best = ov; bidx = oi; }
        }
        if (lane == 0){ cV[wv*U_ + it] = best; cI[wv*U_ + it] = wv*512 + bidx; }
        if (lane == (bidx & 63)) v[bidx >> 6] = -1e30f;
    }
    __syncthreads();
    if (t < 64){
        float v2[6]; int id2[6];
        #pragma unroll
        for (int j = 0; j < 6; j++){
            int slot = t + 64*j;
            if (slot < 8*U_){ v2[j] = cV[slot]; id2[j] = cI[slot]; }
            else            { v2[j] = -1e30f;  id2[j] = 0x7fffffff; }
        }
        for (int it = 0; it < U_; it++){
            float best = -1e30f; int bidx = 0x7fffffff; int bj = 0;
            #pragma unroll
            for (int j = 0; j < 6; j++){
                if (v2[j] > best || (v2[j] == best && id2[j] < bidx)){
                    best = v2[j]; bidx = id2[j]; bj = j;
                }
            }
            float myBest = best; int myIdx = bidx;
            #pragma unroll
            for (int off = 1; off < 64; off <<= 1){
                float ov = __shfl_xor(best, off); int oi = __shfl_xor(bidx, off);
                if (ov > best || (ov == best && oi < bidx)){ best = ov; bidx = oi; }
            }
            if (t == 0) Mtop[bh*U_ + it] = bidx;
            if (myBest == best && myIdx == bidx) v2[bj] = -1e30f;  // unique owner
        }
    }
}

// ---------- fused flash split-k+u: scores + softmax partials + PV + V-sum ----------
// R4 config (uh=2, 1024 blocks) + Q-PRELOAD: all 23 Q rows staged into LDS in
// ONE parallel coalesced burst at block start (one memory latency) instead of
// phase-1's serial per-u {qidx read -> readfirstlane -> 256 B s_load} chain
// (R6 evidence: per-block time scaled ~linearly with u-count -> chain-bound).
// Phase 1 reads Q via wave-uniform LDS broadcasts; collapses to VALU FMA.
__global__ __launch_bounds__(256) void kAttnPart(const float* __restrict__ Qb,
                                                 const float* __restrict__ Kb,
                                                 const float* __restrict__ Vb,
                                                 const int*   __restrict__ Mtop,
                                                 float* __restrict__ Opart,
                                                 float* __restrict__ mlG,
                                                 float* __restrict__ mean){
    int bh = blockIdx.y, b = bh >> 3, h = bh & 7;
    int kc = blockIdx.x, uh = blockIdx.z;
    int u0 = uh ? 23 : 0;
    int nu = uh ? 22 : 23;
    int t = threadIdx.x;
    __shared__ float S[24][260];          // 24.4 KB (rows >= nu zeroed scratch)
    __shared__ float Qs[23][64];          // 5.75 KB staged Q rows
    __shared__ int   qidx[23];

    if (t < nu) qidx[t] = Mtop[bh*U_ + u0 + t];
    // zero scratch rows nu..23 so phase-3 over-read rows contribute 0 (no NaN)
    for (int i = t; i < (24 - nu)*260; i += 256) (&S[nu][0])[i] = 0.f;
    __syncthreads();

    // Q preload: nu*16 float4s, all in flight at once (16 threads per row,
    // 64 B-coalesced chunks of the 256 B rows).
    for (int i = t; i < nu*16; i += 256){
        int r = i >> 4, c = i & 15;
        *(float4*)&Qs[r][c*4] =
            *((const float4*)(Qb + (size_t)b*BSTR_ + (size_t)qidx[r]*STRIDE_ + h*D_) + c);
    }

    // K fragments for this block's 256 keys (independent; overlaps Q preload).
    int k = kc*256 + t;
    float4 kf[16];
    const float4* K4 = (const float4*)(Kb + (size_t)b*BSTR_ + (size_t)k*STRIDE_ + h*D_);
    #pragma unroll
    for (int c = 0; c < 16; c++) kf[c] = K4[c];
    __syncthreads();

    // Phase 1: scores for this block's 256 keys, its nu queries (Q from LDS).
    for (int u = 0; u < nu; u++){
        float a0=0.f, a1=0.f, a2=0.f, a3=0.f;
        #pragma unroll
        for (int c = 0; c < 16; c++){
            float4 qv = *(const float4*)&Qs[u][c*4];   // wave-uniform broadcast
            a0 = fmaf(qv.x, kf[c].x, a0);
            a1 = fmaf(qv.y, kf[c].y, a1);
            a2 = fmaf(qv.z, kf[c].z, a2);
            a3 = fmaf(qv.w, kf[c].w, a3);
        }
        S[u][t] = ((a0+a1)+(a2+a3)) * 0.125f;
    }
    __syncthreads();

    // Phase 2: per-u softmax partial over 256 scores (one wave per u).
    int wv = t >> 6, lane = t & 63;
    for (int u = wv; u < nu; u += 4){
        float4 sv = *(const float4*)&S[u][lane*4];
        float m = fmaxf(fmaxf(sv.x, sv.y), fmaxf(sv.z, sv.w));
        #pragma unroll
        for (int off = 1; off < 64; off <<= 1) m = fmaxf(m, __shfl_xor(m, off));
        float e0 = __expf(sv.x - m), e1 = __expf(sv.y - m);
        float e2 = __expf(sv.z - m), e3 = __expf(sv.w - m);
        float ls = (e0+e1)+(e2+e3);
        #pragma unroll
        for (int off = 1; off < 64; off <<= 1) ls += __shfl_xor(ls, off);
        float4 pv; pv.x = e0; pv.y = e1; pv.z = e2; pv.w = e3;
        *(float4*)&S[u][lane*4] = pv;
        if (lane == 0){
            size_t mi = ((size_t)(bh*KC_ + kc)*U_ + u0 + u)*2;
            mlG[mi] = m; mlG[mi+1] = ls;
        }
    }
    __syncthreads();

    // Phase 3: d-major, shuffle-free. lane d owns output column d;
    // wave w owns u rows [w*6, w*6+6). k-reduction thread-local.
    int d = lane, w = wv;
    int ub = w*6;
    int nuw = nu - ub; if (nuw > 6) nuw = 6; if (nuw < 0) nuw = 0;
    float acc[6];
    #pragma unroll
    for (int j = 0; j < 6; j++) acc[j] = 0.f;
    float vsum = 0.f;
    const float* Vbase = Vb + (size_t)b*BSTR_ + (size_t)(kc*256)*STRIDE_ + h*D_ + d;
    for (int kb = 0; kb < 64; kb++){
        // V[k][d] for 4 consecutive k: wave-coalesced 256 B row reads
        float v0 = Vbase[(size_t)(kb*4+0)*STRIDE_];
        float v1 = Vbase[(size_t)(kb*4+1)*STRIDE_];
        float v2 = Vbase[(size_t)(kb*4+2)*STRIDE_];
        float v3 = Vbase[(size_t)(kb*4+3)*STRIDE_];
        if (uh == 0 && w == 0) vsum += (v0+v1)+(v2+v3);
        #pragma unroll
        for (int j = 0; j < 6; j++){
            float4 p = *(const float4*)&S[ub+j][kb*4];   // wave-uniform broadcast
            acc[j] = fmaf(p.x, v0, acc[j]);
            acc[j] = fmaf(p.y, v1, acc[j]);
            acc[j] = fmaf(p.z, v2, acc[j]);
            acc[j] = fmaf(p.w, v3, acc[j]);
        }
    }
    for (int j = 0; j < nuw; j++)
        Opart[((size_t)(bh*KC_ + kc)*U_ + u0 + ub + j)*64 + d] = acc[j];
    // V column-sum -> mean (SUM). Only uh==0, wave 0 contributes.
    if (uh == 0 && w == 0)
        atomicAdd(&mean[bh*64 + d], vsum);
}

// ---------- output stage A: unconditional mean broadcast (pure NT stream) ----------
__global__ __launch_bounds__(256) void kOutMean(const float* __restrict__ mean,
                                                float* __restrict__ out){
    size_t t = (size_t)blockIdx.x*256 + threadIdx.x;   // one float4; 2,097,152 total
    int d16 = (int)(t & 15); int h = (int)((t >> 4) & 7);
    int b   = (int)(t >> 19);
    int bh = b*8 + h;
    float4 o = *(const float4*)(mean + bh*64 + d16*4);
    const float inv = 1.0f / L_;
    o.x *= inv; o.y *= inv; o.z *= inv; o.w *= inv;
    ntstore4(((float4*)out) + t, o);
}

// ---------- output stage B: split-k merge scatter of the 1440 selected rows ----------
// One wave per (bh,u): wave-uniform scalar mlG merge over 16 kc; lane d reads
// Opart coalesced (256 B/row) and overwrites out[b][Mtop[bh][u]][h][d].
// Runs after kOutMean in-stream, so the overwrite ordering is guaranteed.
__global__ __launch_bounds__(256) void kOutScatter(const int*   __restrict__ Mtop,
                                                   const float* __restrict__ mlG,
                                                   const float* __restrict__ Opart,
                                                   float* __restrict__ out){
    int gid = blockIdx.x*4 + (threadIdx.x >> 6);   // 0..1439 = bh*U_ + u
    int lane = threadIdx.x & 63;
    int bh = gid / U_, u = gid % U_;
    int b = bh >> 3, h = bh & 7;
    int l = Mtop[bh*U_ + u];                       // wave-uniform
    float mstar = -1e30f;
    #pragma unroll
    for (int kc = 0; kc < KC_; kc++)
        mstar = fmaxf(mstar, mlG[((size_t)(bh*KC_ + kc)*U_ + u)*2]);
    float lsum = 0.f, acc = 0.f;
    #pragma unroll
    for (int kc = 0; kc < KC_; kc++){
        size_t mi = ((size_t)(bh*KC_ + kc)*U_ + u)*2;
        float wgt = __expf(mlG[mi] - mstar);
        lsum = fmaf(mlG[mi+1], wgt, lsum);
        acc  = fmaf(wgt, Opart[((size_t)(bh*KC_ + kc)*U_ + u)*64 + lane], acc);
    }
    out[((size_t)b*L_ + (size_t)l)*STRIDE_ + h*D_ + lane] = acc / lsum;
}

extern "C" void kernel_launch(void* const* d_in, const int* in_sizes, int n_in,
                              void* d_out, int out_size, void* d_ws, size_t ws_size,
                              hipStream_t stream) {
    const float* Qb  = (const float*)d_in[0];
    const float* Kb  = (const float*)d_in[1];
    const float* Vb  = (const float*)d_in[2];
    const int*   idx = (const int*)d_in[3];
    float* out = (float*)d_out;

    float* ws = (float*)d_ws;
    // ws layout (float offsets)
    float* M      = ws;                      // 131072
    int*   Mtop   = (int*)(ws + 131072);     // 1440 (pad 2048)
    float* mean   = ws + 133120;             // 2048 (SUM; zeroed in kTopF, scaled in kOutMean)
    float* mlG    = ws + 266240;             // 32*16*45*2 = 46080 (pad 49152)
    float* Opart  = ws + 315392;             // 32*16*45*64 = 1474560
    // total = 1,789,952 floats = 7.2 MB

    kM         <<<dim3(2048),       dim3(256), 0, stream>>>(Qb, Kb, idx, M);
    kTopF      <<<dim3(32),         dim3(512), 0, stream>>>(M, Mtop, mean);
    kAttnPart  <<<dim3(KC_, 32, 2), dim3(256), 0, stream>>>(Qb, Kb, Vb, Mtop, Opart, mlG, mean);
    kOutMean   <<<dim3(8192),       dim3(256), 0, stream>>>(mean, out);
    kOutScatter<<<dim3(360),        dim3(256), 0, stream>>>(Mtop, mlG, Opart, out);
}

// Round 10
// 323.449 us; speedup vs baseline: 1.0341x; 1.0341x over previous
//
#include <hip/hip_runtime.h>
#include <stdint.h>

#define B_ 4
#define L_ 4096
#define H_ 8
#define D_ 64
#define S_ 45
#define U_ 45
#define BH_ 32
#define KC_ 16                     // split-k chunks (256 keys each)
#define STRIDE_ (H_*D_)            // 512 floats between consecutive l
#define BSTR_ ((size_t)L_*H_*D_)   // 2097152 floats per batch

// index_sample declared int64 in the reference; harness may pass int32 or int64.
__device__ __forceinline__ bool detect_idx64(const int* idxp){
    bool z = true;
    #pragma unroll
    for (int i = 1; i < 32; i += 2) z = z && (idxp[i] == 0);
    return z;
}

// Nontemporal float4 load/store (HIP float4 is a struct; go through ext_vector).
typedef float v4f_ __attribute__((ext_vector_type(4)));
__device__ __forceinline__ float4 ntload4(const float4* p){
    v4f_ v = __builtin_nontemporal_load((const v4f_*)p);
    return make_float4(v.x, v.y, v.z, v.w);
}
__device__ __forceinline__ void ntstore4(float4* p, float4 f){
    v4f_ v; v.x = f.x; v.y = f.y; v.z = f.z; v.w = f.w;
    __builtin_nontemporal_store(v, (v4f_*)p);
}

// ---------- kernel A: M[bh][q] = max_s(dot) - sum_s(dot)/L ----------
// WAVE-PER-SAMPLE contiguous gather: one sample row = K[b, ki, hg*4..+3, :] =
// 1 KB; lane l reads float4 #l -> each vmem instr is ONE contiguous 1 KB burst
// (8 consecutive lines -> 8 distinct L2 channels, deterministic) vs the old
// 4-scattered-256B-segments-per-instr. Bytes/lines/instr-count invariant;
// tests the channel/tag-imbalance theory for the 57%-of-L2 gather plateau.
// Hot K slice stays 4.0 MB/XCD (g&7 -> one (b,hg) per XCD; 8 MB thrashes, R5).
// Reduction: 4 shuffles/sample within 16-lane groups; head = lane>>4.
__global__ __launch_bounds__(256) void kM(const float* __restrict__ Qb,
                                          const float* __restrict__ Kb,
                                          const int* __restrict__ idxp,
                                          float* __restrict__ Mout){
    int g = blockIdx.x;                 // 0..2047
    int grp8 = g & 7;                   // one (b, head-half) per XCD
    int b  = grp8 >> 1;
    int hg = grp8 & 1;
    int chunk = g >> 3;                 // 0..255
    int q0 = chunk * 16;
    bool idx64 = detect_idx64(idxp);

    __shared__ int lidx[16*S_];         // 2.88 KB: this block's 16 q x 45 idx
    for (int i = threadIdx.x; i < 16*S_; i += 256)
        lidx[i] = idx64 ? __builtin_nontemporal_load(&idxp[2*(q0*S_ + i)])
                        : __builtin_nontemporal_load(&idxp[q0*S_ + i]);
    __syncthreads();

    int lane = threadIdx.x & 63;
    int w    = threadIdx.x >> 6;        // wave 0..3
    int hd   = lane >> 4;               // head within half: 0..3
    int l16  = lane & 15;               // dim-quad within head

    const float4* qbase = (const float4*)(Qb + (size_t)b*BSTR_ + hg*256);
    const float4* kbase = (const float4*)(Kb + (size_t)b*BSTR_ + hg*256);

    #pragma unroll
    for (int i = 0; i < 4; i++){
        int ql = w*4 + i;               // 0..15
        int q  = q0 + ql;
        // Q fragment: lane l -> head hg*4+hd, dims l16*4..+3 (1 KB wave-contig)
        float4 qf = ntload4(qbase + (size_t)q*128 + lane);
        const int* myIdx = &lidx[ql*S_];
        float mx = -1e30f, sm = 0.f;
        #pragma unroll 5
        for (int s = 0; s < S_; s++){
            int ki = myIdx[s];          // wave-uniform
            float4 k4 = kbase[(size_t)ki*128 + lane];   // 1 KB contiguous burst
            float p = qf.x*k4.x;
            p = fmaf(qf.y, k4.y, p);
            p = fmaf(qf.z, k4.z, p);
            p = fmaf(qf.w, k4.w, p);
            // 16-lane group reduce -> per-head 64-dim dot
            p += __shfl_xor(p, 1);
            p += __shfl_xor(p, 2);
            p += __shfl_xor(p, 4);
            p += __shfl_xor(p, 8);
            mx = fmaxf(mx, p); sm += p;
        }
        if (l16 == 0)
            __builtin_nontemporal_store(mx - sm*(1.0f/L_),
                &Mout[(size_t)(b*8 + hg*4 + hd)*L_ + q]);
    }
}

// ---------- fused top-45 per (b,h) + mean zero (selRow eliminated, R8) ----------
__global__ __launch_bounds__(512) void kTopF(const float* __restrict__ M,
                                             int* __restrict__ Mtop,
                                             float* __restrict__ meanZ){
    int bh = blockIdx.x;
    int t = threadIdx.x;
    if (t < 64) meanZ[bh*64 + t] = 0.f;

    __shared__ float cV[8*U_];
    __shared__ int   cI[8*U_];
    int wv = t >> 6, lane = t & 63;      // wv = segment 0..7
    const float* Mr = M + (size_t)bh*L_ + wv*512;
    float v[8];
    #pragma unroll
    for (int j = 0; j < 8; j++) v[j] = Mr[lane + 64*j];

    for (int it = 0; it < U_; it++){
        float best = -1e30f; int bidx = 0x7fffffff;
        #pragma unroll
        for (int j = 0; j < 8; j++){
            int id = lane + 64*j;
            if (v[j] > best){ best = v[j]; bidx = id; }   // ascending id scan
        }
        #pragma unroll
        for (int off = 1; off < 64; off <<= 1){
            float ov = __shfl_xor(best, off); int oi = __shfl_xor(bidx, off);
            if (ov > best || (ov == best && oi < bidx)){ best = ov; bidx = oi; }
        }
        if (lane == 0){ cV[wv*U_ + it] = best; cI[wv*U_ + it] = wv*512 + bidx; }
        if (lane == (bidx & 63)) v[bidx >> 6] = -1e30f;
    }
    __syncthreads();
    if (t < 64){
        float v2[6]; int id2[6];
        #pragma unroll
        for (int j = 0; j < 6; j++){
            int slot = t + 64*j;
            if (slot < 8*U_){ v2[j] = cV[slot]; id2[j] = cI[slot]; }
            else            { v2[j] = -1e30f;  id2[j] = 0x7fffffff; }
        }
        for (int it = 0; it < U_; it++){
            float best = -1e30f; int bidx = 0x7fffffff; int bj = 0;
            #pragma unroll
            for (int j = 0; j < 6; j++){
                if (v2[j] > best || (v2[j] == best && id2[j] < bidx)){
                    best = v2[j]; bidx = id2[j]; bj = j;
                }
            }
            float myBest = best; int myIdx = bidx;
            #pragma unroll
            for (int off = 1; off < 64; off <<= 1){
                float ov = __shfl_xor(best, off); int oi = __shfl_xor(bidx, off);
                if (ov > best || (ov == best && oi < bidx)){ best = ov; bidx = oi; }
            }
            if (t == 0) Mtop[bh*U_ + it] = bidx;
            if (myBest == best && myIdx == bidx) v2[bj] = -1e30f;  // unique owner
        }
    }
}

// ---------- fused flash split-k+u: scores + softmax partials + PV + V-sum ----------
// R8-BEST config restored (uh=2, 1024 blocks, ~25 KB LDS; Q via readfirstlane
// scalar loads — R9 proved LDS-staged Q regresses: +370 ds_reads/wave on the
// DS pipe and lgkmcnt-serialized phase 1). Phase 3 d-major shuffle-free.
__global__ __launch_bounds__(256) void kAttnPart(const float* __restrict__ Qb,
                                                 const float* __restrict__ Kb,
                                                 const float* __restrict__ Vb,
                                                 const int*   __restrict__ Mtop,
                                                 float* __restrict__ Opart,
                                                 float* __restrict__ mlG,
                                                 float* __restrict__ mean){
    int bh = blockIdx.y, b = bh >> 3, h = bh & 7;
    int kc = blockIdx.x, uh = blockIdx.z;
    int u0 = uh ? 23 : 0;
    int nu = uh ? 22 : 23;
    int t = threadIdx.x;
    __shared__ float S[24][260];          // 24.4 KB (rows >= nu zeroed scratch)
    __shared__ int   qidx[23];

    if (t < nu) qidx[t] = Mtop[bh*U_ + u0 + t];
    // zero scratch rows nu..23 so phase-3 over-read rows contribute 0 (no NaN)
    for (int i = t; i < (24 - nu)*260; i += 256) (&S[nu][0])[i] = 0.f;
    __syncthreads();

    // Phase 1: scores for this block's 256 keys, its nu queries.
    int k = kc*256 + t;
    float4 kf[16];
    const float4* K4 = (const float4*)(Kb + (size_t)b*BSTR_ + (size_t)k*STRIDE_ + h*D_);
    #pragma unroll
    for (int c = 0; c < 16; c++) kf[c] = K4[c];
    for (int u = 0; u < nu; u++){
        int qi = __builtin_amdgcn_readfirstlane(qidx[u]);   // wave-uniform -> scalar loads
        const float4* qp = (const float4*)(Qb + (size_t)b*BSTR_ + (size_t)qi*STRIDE_ + h*D_);
        float a0=0.f, a1=0.f, a2=0.f, a3=0.f;
        #pragma unroll
        for (int c = 0; c < 16; c++){
            float4 qv = qp[c];
            a0 = fmaf(qv.x, kf[c].x, a0);
            a1 = fmaf(qv.y, kf[c].y, a1);
            a2 = fmaf(qv.z, kf[c].z, a2);
            a3 = fmaf(qv.w, kf[c].w, a3);
        }
        S[u][t] = ((a0+a1)+(a2+a3)) * 0.125f;
    }
    __syncthreads();

    // Phase 2: per-u softmax partial over 256 scores (one wave per u).
    int wv = t >> 6, lane = t & 63;
    for (int u = wv; u < nu; u += 4){
        float4 sv = *(const float4*)&S[u][lane*4];
        float m = fmaxf(fmaxf(sv.x, sv.y), fmaxf(sv.z, sv.w));
        #pragma unroll
        for (int off = 1; off < 64; off <<= 1) m = fmaxf(m, __shfl_xor(m, off));
        float e0 = __expf(sv.x - m), e1 = __expf(sv.y - m);
        float e2 = __expf(sv.z - m), e3 = __expf(sv.w - m);
        float ls = (e0+e1)+(e2+e3);
        #pragma unroll
        for (int off = 1; off < 64; off <<= 1) ls += __shfl_xor(ls, off);
        float4 pv; pv.x = e0; pv.y = e1; pv.z = e2; pv.w = e3;
        *(float4*)&S[u][lane*4] = pv;
        if (lane == 0){
            size_t mi = ((size_t)(bh*KC_ + kc)*U_ + u0 + u)*2;
            mlG[mi] = m; mlG[mi+1] = ls;
        }
    }
    __syncthreads();

    // Phase 3: d-major, shuffle-free. lane d owns output column d;
    // wave w owns u rows [w*6, w*6+6). k-reduction thread-local.
    int d = lane, w = wv;
    int ub = w*6;
    int nuw = nu - ub; if (nuw > 6) nuw = 6; if (nuw < 0) nuw = 0;
    float acc[6];
    #pragma unroll
    for (int j = 0; j < 6; j++) acc[j] = 0.f;
    float vsum = 0.f;
    const float* Vbase = Vb + (size_t)b*BSTR_ + (size_t)(kc*256)*STRIDE_ + h*D_ + d;
    for (int kb = 0; kb < 64; kb++){
        // V[k][d] for 4 consecutive k: wave-coalesced 256 B row reads
        float v0 = Vbase[(size_t)(kb*4+0)*STRIDE_];
        float v1 = Vbase[(size_t)(kb*4+1)*STRIDE_];
        float v2 = Vbase[(size_t)(kb*4+2)*STRIDE_];
        float v3 = Vbase[(size_t)(kb*4+3)*STRIDE_];
        if (uh == 0 && w == 0) vsum += (v0+v1)+(v2+v3);
        #pragma unroll
        for (int j = 0; j < 6; j++){
            float4 p = *(const float4*)&S[ub+j][kb*4];   // wave-uniform broadcast
            acc[j] = fmaf(p.x, v0, acc[j]);
            acc[j] = fmaf(p.y, v1, acc[j]);
            acc[j] = fmaf(p.z, v2, acc[j]);
            acc[j] = fmaf(p.w, v3, acc[j]);
        }
    }
    for (int j = 0; j < nuw; j++)
        Opart[((size_t)(bh*KC_ + kc)*U_ + u0 + ub + j)*64 + d] = acc[j];
    // V column-sum -> mean (SUM). Only uh==0, wave 0 contributes.
    if (uh == 0 && w == 0)
        atomicAdd(&mean[bh*64 + d], vsum);
}

// ---------- output stage A: unconditional mean broadcast (pure NT stream) ----------
__global__ __launch_bounds__(256) void kOutMean(const float* __restrict__ mean,
                                                float* __restrict__ out){
    size_t t = (size_t)blockIdx.x*256 + threadIdx.x;   // one float4; 2,097,152 total
    int d16 = (int)(t & 15); int h = (int)((t >> 4) & 7);
    int b   = (int)(t >> 19);
    int bh = b*8 + h;
    float4 o = *(const float4*)(mean + bh*64 + d16*4);
    const float inv = 1.0f / L_;
    o.x *= inv; o.y *= inv; o.z *= inv; o.w *= inv;
    ntstore4(((float4*)out) + t, o);
}

// ---------- output stage B: split-k merge scatter of the 1440 selected rows ----------
// One wave per (bh,u): wave-uniform scalar mlG merge over 16 kc; lane d reads
// Opart coalesced (256 B/row) and overwrites out[b][Mtop[bh][u]][h][d].
// Runs after kOutMean in-stream, so the overwrite ordering is guaranteed.
__global__ __launch_bounds__(256) void kOutScatter(const int*   __restrict__ Mtop,
                                                   const float* __restrict__ mlG,
                                                   const float* __restrict__ Opart,
                                                   float* __restrict__ out){
    int gid = blockIdx.x*4 + (threadIdx.x >> 6);   // 0..1439 = bh*U_ + u
    int lane = threadIdx.x & 63;
    int bh = gid / U_, u = gid % U_;
    int b = bh >> 3, h = bh & 7;
    int l = Mtop[bh*U_ + u];                       // wave-uniform
    float mstar = -1e30f;
    #pragma unroll
    for (int kc = 0; kc < KC_; kc++)
        mstar = fmaxf(mstar, mlG[((size_t)(bh*KC_ + kc)*U_ + u)*2]);
    float lsum = 0.f, acc = 0.f;
    #pragma unroll
    for (int kc = 0; kc < KC_; kc++){
        size_t mi = ((size_t)(bh*KC_ + kc)*U_ + u)*2;
        float wgt = __expf(mlG[mi] - mstar);
        lsum = fmaf(mlG[mi+1], wgt, lsum);
        acc  = fmaf(wgt, Opart[((size_t)(bh*KC_ + kc)*U_ + u)*64 + lane], acc);
    }
    out[((size_t)b*L_ + (size_t)l)*STRIDE_ + h*D_ + lane] = acc / lsum;
}

extern "C" void kernel_launch(void* const* d_in, const int* in_sizes, int n_in,
                              void* d_out, int out_size, void* d_ws, size_t ws_size,
                              hipStream_t stream) {
    const float* Qb  = (const float*)d_in[0];
    const float* Kb  = (const float*)d_in[1];
    const float* Vb  = (const float*)d_in[2];
    const int*   idx = (const int*)d_in[3];
    float* out = (float*)d_out;

    float* ws = (float*)d_ws;
    // ws layout (float offsets)
    float* M      = ws;                      // 131072
    int*   Mtop   = (int*)(ws + 131072);     // 1440 (pad 2048)
    float* mean   = ws + 133120;             // 2048 (SUM; zeroed in kTopF, scaled in kOutMean)
    float* mlG    = ws + 266240;             // 32*16*45*2 = 46080 (pad 49152)
    float* Opart  = ws + 315392;             // 32*16*45*64 = 1474560
    // total = 1,789,952 floats = 7.2 MB

    kM         <<<dim3(2048),       dim3(256), 0, stream>>>(Qb, Kb, idx, M);
    kTopF      <<<dim3(32),         dim3(512), 0, stream>>>(M, Mtop, mean);
    kAttnPart  <<<dim3(KC_, 32, 2), dim3(256), 0, stream>>>(Qb, Kb, Vb, Mtop, Opart, mlG, mean);
    kOutMean   <<<dim3(8192),       dim3(256), 0, stream>>>(mean, out);
    kOutScatter<<<dim3(360),        dim3(256), 0, stream>>>(Mtop, mlG, Opart, out);
}

// Round 11
// 307.382 us; speedup vs baseline: 1.0881x; 1.0523x over previous
//
#include <hip/hip_runtime.h>
#include <stdint.h>

#define B_ 4
#define L_ 4096
#define H_ 8
#define D_ 64
#define S_ 45
#define U_ 45
#define BH_ 32
#define KC_ 16                     // split-k chunks (256 keys each)
#define STRIDE_ (H_*D_)            // 512 floats between consecutive l
#define BSTR_ ((size_t)L_*H_*D_)   // 2097152 floats per batch

// index_sample declared int64 in the reference; harness may pass int32 or int64.
__device__ __forceinline__ bool detect_idx64(const int* idxp){
    bool z = true;
    #pragma unroll
    for (int i = 1; i < 32; i += 2) z = z && (idxp[i] == 0);
    return z;
}

// Nontemporal float4 load/store (HIP float4 is a struct; go through ext_vector).
typedef float v4f_ __attribute__((ext_vector_type(4)));
__device__ __forceinline__ float4 ntload4(const float4* p){
    v4f_ v = __builtin_nontemporal_load((const v4f_*)p);
    return make_float4(v.x, v.y, v.z, v.w);
}
__device__ __forceinline__ void ntstore4(float4* p, float4 f){
    v4f_ v; v.x = f.x; v.y = f.y; v.z = f.z; v.w = f.w;
    __builtin_nontemporal_store(v, (v4f_*)p);
}

// ---------- kernel A: M[bh][q] = max_s(dot) - sum_s(dot)/L ----------
// R4-BEST STRUCTURE — DECLARED FLOOR. 4-head-fused gather: one sample row =
// K[b, ki, hg*4..+3, :] = 1 KB contiguous; 16-lane group per q gives 4
// independent gather streams per wave instr (R10's wave-per-sample serial
// variant regressed 77->98). One (b,hg) per XCD via g&7 -> 4.0 MB hot K slice
// (8 MB thrashes, R5). FETCH == compulsory -> no capacity miss; 77 us =
// 2.45 TB/s/XCD = ~57% of L2 streaming rate = random-channel queuing
// asymptote (~1-1/e). NT/packing/preload variants: all null or negative.
__global__ __launch_bounds__(256) void kM(const float* __restrict__ Qb,
                                          const float* __restrict__ Kb,
                                          const int* __restrict__ idxp,
                                          float* __restrict__ Mout){
    int g = blockIdx.x;                 // 0..2047
    int grp8 = g & 7;                   // one (b, head-half) per XCD
    int b  = grp8 >> 1;
    int hg = grp8 & 1;
    int chunk = g >> 3;                 // 0..255
    int q0 = chunk * 16;
    bool idx64 = detect_idx64(idxp);

    __shared__ int lidx[16*S_];         // 2.88 KB: this block's 16 q x 45 idx
    for (int i = threadIdx.x; i < 16*S_; i += 256)
        lidx[i] = idx64 ? __builtin_nontemporal_load(&idxp[2*(q0*S_ + i)])
                        : __builtin_nontemporal_load(&idxp[q0*S_ + i]);
    __syncthreads();

    int lane = threadIdx.x & 63;
    int w    = threadIdx.x >> 6;        // wave 0..3
    int grp  = lane >> 4;               // 16-lane group: one q each
    int l16  = lane & 15;
    int ql   = w*4 + grp;               // 0..15
    int q    = q0 + ql;

    const float4* qr = (const float4*)(Qb + (size_t)b*BSTR_ + (size_t)q*STRIDE_ + hg*256);
    float4 qf0 = ntload4(qr + l16);        // head hg*4+0, dims l16*4..+3
    float4 qf1 = ntload4(qr + 16 + l16);   // head hg*4+1
    float4 qf2 = ntload4(qr + 32 + l16);   // head hg*4+2
    float4 qf3 = ntload4(qr + 48 + l16);   // head hg*4+3

    const float* kbase = Kb + (size_t)b*BSTR_ + hg*256;
    // lane<8 of each group accumulates heads {0,1}; lane>=8 heads {2,3}
    float mxa = -1e30f, mxb = -1e30f, sma = 0.f, smb = 0.f;
    const int* myIdx = &lidx[ql*S_];

    #pragma unroll 3
    for (int s = 0; s < S_; s++){
        int ki = myIdx[s];              // broadcast within group
        const float4* kr = (const float4*)(kbase + (size_t)ki*STRIDE_);
        float4 k0 = kr[l16], k1 = kr[16+l16], k2 = kr[32+l16], k3 = kr[48+l16];
        float p0 = qf0.x*k0.x; p0 = fmaf(qf0.y,k0.y,p0); p0 = fmaf(qf0.z,k0.z,p0); p0 = fmaf(qf0.w,k0.w,p0);
        float p1 = qf1.x*k1.x; p1 = fmaf(qf1.y,k1.y,p1); p1 = fmaf(qf1.z,k1.z,p1); p1 = fmaf(qf1.w,k1.w,p1);
        float p2 = qf2.x*k2.x; p2 = fmaf(qf2.y,k2.y,p2); p2 = fmaf(qf2.z,k2.z,p2); p2 = fmaf(qf2.w,k2.w,p2);
        float p3 = qf3.x*k3.x; p3 = fmaf(qf3.y,k3.y,p3); p3 = fmaf(qf3.z,k3.z,p3); p3 = fmaf(qf3.w,k3.w,p3);
        // fold the two 8-lane halves of each head partial (1 shfl each)
        float u0 = p0 + __shfl_xor(p0, 8);
        float u1 = p1 + __shfl_xor(p1, 8);
        float u2 = p2 + __shfl_xor(p2, 8);
        float u3 = p3 + __shfl_xor(p3, 8);
        // lane specialization: low half carries heads 0/1, high half 2/3
        float va = (l16 < 8) ? u0 : u2;
        float vb = (l16 < 8) ? u1 : u3;
        #pragma unroll
        for (int off = 1; off < 8; off <<= 1){
            va += __shfl_xor(va, off);
            vb += __shfl_xor(vb, off);
        }
        mxa = fmaxf(mxa, va); sma += va;
        mxb = fmaxf(mxb, vb); smb += vb;
    }
    // writers: l16==0 -> head0(a), l16==1 -> head1(b), l16==8 -> head2(a), l16==9 -> head3(b)
    int hsel = (l16==0) ? 0 : (l16==1) ? 1 : (l16==8) ? 2 : (l16==9) ? 3 : -1;
    if (hsel >= 0){
        float mv = (l16 & 1) ? mxb : mxa;
        float sv = (l16 & 1) ? smb : sma;
        __builtin_nontemporal_store(mv - sv*(1.0f/L_),
            &Mout[(size_t)(b*8 + hg*4 + hsel)*L_ + q]);
    }
}

// ---------- fused top-45 per (b,h) + mean zero + compact uint16 selRow ----------
// selRow16: 32 bh x 4096 uint16 = 256 KB (NOT the 16.7 MB I mis-estimated in
// R8 — it was 512 KB as int; uint16 halves it). Re-added to enable single
// fused output kernel (kills the separate scatter launch + double-write).
__global__ __launch_bounds__(512) void kTopF(const float* __restrict__ M,
                                             int* __restrict__ Mtop,
                                             float* __restrict__ meanZ,
                                             unsigned short* __restrict__ selRow16){
    int bh = blockIdx.x;
    int t = threadIdx.x;
    if (t < 64) meanZ[bh*64 + t] = 0.f;
    for (int j = t; j < L_; j += 512) selRow16[(size_t)bh*L_ + j] = 0;

    __shared__ float cV[8*U_];
    __shared__ int   cI[8*U_];
    int wv = t >> 6, lane = t & 63;      // wv = segment 0..7
    const float* Mr = M + (size_t)bh*L_ + wv*512;
    float v[8];
    #pragma unroll
    for (int j = 0; j < 8; j++) v[j] = Mr[lane + 64*j];

    for (int it = 0; it < U_; it++){
        float best = -1e30f; int bidx = 0x7fffffff;
        #pragma unroll
        for (int j = 0; j < 8; j++){
            int id = lane + 64*j;
            if (v[j] > best){ best = v[j]; bidx = id; }   // ascending id scan
        }
        #pragma unroll
        for (int off = 1; off < 64; off <<= 1){
            float ov = __shfl_xor(best, off); int oi = __shfl_xor(bidx, off);
            if (ov > best || (ov == best && oi < bidx)){ best = ov; bidx = oi; }
        }
        if (lane == 0){ cV[wv*U_ + it] = best; cI[wv*U_ + it] = wv*512 + bidx; }
        if (lane == (bidx & 63)) v[bidx >> 6] = -1e30f;
    }
    __syncthreads();
    if (t < 64){
        float v2[6]; int id2[6];
        #pragma unroll
        for (int j = 0; j < 6; j++){
            int slot = t + 64*j;
            if (slot < 8*U_){ v2[j] = cV[slot]; id2[j] = cI[slot]; }
            else            { v2[j] = -1e30f;  id2[j] = 0x7fffffff; }
        }
        for (int it = 0; it < U_; it++){
            float best = -1e30f; int bidx = 0x7fffffff; int bj = 0;
            #pragma unroll
            for (int j = 0; j < 6; j++){
                if (v2[j] > best || (v2[j] == best && id2[j] < bidx)){
                    best = v2[j]; bidx = id2[j]; bj = j;
                }
            }
            float myBest = best; int myIdx = bidx;
            #pragma unroll
            for (int off = 1; off < 64; off <<= 1){
                float ov = __shfl_xor(best, off); int oi = __shfl_xor(bidx, off);
                if (ov > best || (ov == best && oi < bidx)){ best = ov; bidx = oi; }
            }
            if (t == 0){
                Mtop[bh*U_ + it] = bidx;
                selRow16[(size_t)bh*L_ + bidx] = (unsigned short)(it + 1);
            }
            if (myBest == best && myIdx == bidx) v2[bj] = -1e30f;  // unique owner
        }
    }
}

// ---------- fused flash split-k+u: scores + softmax partials + PV + V-sum ----------
// R8-BEST config — UNTOUCHED (uh=2, 1024 blocks, ~25 KB LDS; Q via
// readfirstlane scalar loads — LDS-staged Q regressed (R9), wave-per-sample
// regressed (R10 analog)). Phase 3 d-major shuffle-free.
__global__ __launch_bounds__(256) void kAttnPart(const float* __restrict__ Qb,
                                                 const float* __restrict__ Kb,
                                                 const float* __restrict__ Vb,
                                                 const int*   __restrict__ Mtop,
                                                 float* __restrict__ Opart,
                                                 float* __restrict__ mlG,
                                                 float* __restrict__ mean){
    int bh = blockIdx.y, b = bh >> 3, h = bh & 7;
    int kc = blockIdx.x, uh = blockIdx.z;
    int u0 = uh ? 23 : 0;
    int nu = uh ? 22 : 23;
    int t = threadIdx.x;
    __shared__ float S[24][260];          // 24.4 KB (rows >= nu zeroed scratch)
    __shared__ int   qidx[23];

    if (t < nu) qidx[t] = Mtop[bh*U_ + u0 + t];
    // zero scratch rows nu..23 so phase-3 over-read rows contribute 0 (no NaN)
    for (int i = t; i < (24 - nu)*260; i += 256) (&S[nu][0])[i] = 0.f;
    __syncthreads();

    // Phase 1: scores for this block's 256 keys, its nu queries.
    int k = kc*256 + t;
    float4 kf[16];
    const float4* K4 = (const float4*)(Kb + (size_t)b*BSTR_ + (size_t)k*STRIDE_ + h*D_);
    #pragma unroll
    for (int c = 0; c < 16; c++) kf[c] = K4[c];
    for (int u = 0; u < nu; u++){
        int qi = __builtin_amdgcn_readfirstlane(qidx[u]);   // wave-uniform -> scalar loads
        const float4* qp = (const float4*)(Qb + (size_t)b*BSTR_ + (size_t)qi*STRIDE_ + h*D_);
        float a0=0.f, a1=0.f, a2=0.f, a3=0.f;
        #pragma unroll
        for (int c = 0; c < 16; c++){
            float4 qv = qp[c];
            a0 = fmaf(qv.x, kf[c].x, a0);
            a1 = fmaf(qv.y, kf[c].y, a1);
            a2 = fmaf(qv.z, kf[c].z, a2);
            a3 = fmaf(qv.w, kf[c].w, a3);
        }
        S[u][t] = ((a0+a1)+(a2+a3)) * 0.125f;
    }
    __syncthreads();

    // Phase 2: per-u softmax partial over 256 scores (one wave per u).
    int wv = t >> 6, lane = t & 63;
    for (int u = wv; u < nu; u += 4){
        float4 sv = *(const float4*)&S[u][lane*4];
        float m = fmaxf(fmaxf(sv.x, sv.y), fmaxf(sv.z, sv.w));
        #pragma unroll
        for (int off = 1; off < 64; off <<= 1) m = fmaxf(m, __shfl_xor(m, off));
        float e0 = __expf(sv.x - m), e1 = __expf(sv.y - m);
        float e2 = __expf(sv.z - m), e3 = __expf(sv.w - m);
        float ls = (e0+e1)+(e2+e3);
        #pragma unroll
        for (int off = 1; off < 64; off <<= 1) ls += __shfl_xor(ls, off);
        float4 pv; pv.x = e0; pv.y = e1; pv.z = e2; pv.w = e3;
        *(float4*)&S[u][lane*4] = pv;
        if (lane == 0){
            size_t mi = ((size_t)(bh*KC_ + kc)*U_ + u0 + u)*2;
            mlG[mi] = m; mlG[mi+1] = ls;
        }
    }
    __syncthreads();

    // Phase 3: d-major, shuffle-free. lane d owns output column d;
    // wave w owns u rows [w*6, w*6+6). k-reduction thread-local.
    int d = lane, w = wv;
    int ub = w*6;
    int nuw = nu - ub; if (nuw > 6) nuw = 6; if (nuw < 0) nuw = 0;
    float acc[6];
    #pragma unroll
    for (int j = 0; j < 6; j++) acc[j] = 0.f;
    float vsum = 0.f;
    const float* Vbase = Vb + (size_t)b*BSTR_ + (size_t)(kc*256)*STRIDE_ + h*D_ + d;
    for (int kb = 0; kb < 64; kb++){
        // V[k][d] for 4 consecutive k: wave-coalesced 256 B row reads
        float v0 = Vbase[(size_t)(kb*4+0)*STRIDE_];
        float v1 = Vbase[(size_t)(kb*4+1)*STRIDE_];
        float v2 = Vbase[(size_t)(kb*4+2)*STRIDE_];
        float v3 = Vbase[(size_t)(kb*4+3)*STRIDE_];
        if (uh == 0 && w == 0) vsum += (v0+v1)+(v2+v3);
        #pragma unroll
        for (int j = 0; j < 6; j++){
            float4 p = *(const float4*)&S[ub+j][kb*4];   // wave-uniform broadcast
            acc[j] = fmaf(p.x, v0, acc[j]);
            acc[j] = fmaf(p.y, v1, acc[j]);
            acc[j] = fmaf(p.z, v2, acc[j]);
            acc[j] = fmaf(p.w, v3, acc[j]);
        }
    }
    for (int j = 0; j < nuw; j++)
        Opart[((size_t)(bh*KC_ + kc)*U_ + u0 + ub + j)*64 + d] = acc[j];
    // V column-sum -> mean (SUM). Only uh==0, wave 0 contributes.
    if (uh == 0 && w == 0)
        atomicAdd(&mean[bh*64 + d], vsum);
}

// ---------- fused output: mean fill + inline split-k merge (one kernel) ----------
// selRow16 lookup per (bh,l): 16 consecutive threads share one uint16 ->
// broadcast load. 0.35% of threads take the 16-kc merge branch inline; the
// branch is uniform within each 16-thread group (divergence negligible).
// Kills the separate scatter launch and the double-write of selected rows.
__global__ __launch_bounds__(256) void kOut(const float* __restrict__ mean,
                                            const unsigned short* __restrict__ selRow16,
                                            const float* __restrict__ mlG,
                                            const float* __restrict__ Opart,
                                            float* __restrict__ out){
    size_t t = (size_t)blockIdx.x*256 + threadIdx.x;   // one float4; 2,097,152 total
    int d16 = (int)(t & 15); int h = (int)((t >> 4) & 7);
    int l   = (int)((t >> 7) & 4095); int b = (int)(t >> 19);
    int bh = b*8 + h;
    int sel = selRow16[(size_t)bh*L_ + l];
    float4 o;
    if (sel == 0){
        o = *(const float4*)(mean + bh*64 + d16*4);
        const float inv = 1.0f / L_;
        o.x *= inv; o.y *= inv; o.z *= inv; o.w *= inv;
    } else {
        int u = sel - 1;
        float mstar = -1e30f;
        #pragma unroll
        for (int kc = 0; kc < KC_; kc++)
            mstar = fmaxf(mstar, mlG[((size_t)(bh*KC_ + kc)*U_ + u)*2]);
        float lsum = 0.f;
        float4 acc; acc.x = acc.y = acc.z = acc.w = 0.f;
        #pragma unroll
        for (int kc = 0; kc < KC_; kc++){
            size_t mi = ((size_t)(bh*KC_ + kc)*U_ + u)*2;
            float wgt = __expf(mlG[mi] - mstar);
            lsum = fmaf(mlG[mi+1], wgt, lsum);
            float4 op = *(const float4*)(Opart + ((size_t)(bh*KC_ + kc)*U_ + u)*64 + d16*4);
            acc.x = fmaf(wgt, op.x, acc.x);
            acc.y = fmaf(wgt, op.y, acc.y);
            acc.z = fmaf(wgt, op.z, acc.z);
            acc.w = fmaf(wgt, op.w, acc.w);
        }
        float inv = 1.0f / lsum;
        acc.x *= inv; acc.y *= inv; acc.z *= inv; acc.w *= inv;
        o = acc;
    }
    ntstore4(((float4*)out) + t, o);
}

extern "C" void kernel_launch(void* const* d_in, const int* in_sizes, int n_in,
                              void* d_out, int out_size, void* d_ws, size_t ws_size,
                              hipStream_t stream) {
    const float* Qb  = (const float*)d_in[0];
    const float* Kb  = (const float*)d_in[1];
    const float* Vb  = (const float*)d_in[2];
    const int*   idx = (const int*)d_in[3];
    float* out = (float*)d_out;

    float* ws = (float*)d_ws;
    // ws layout (float offsets)
    float* M      = ws;                              // 131072
    int*   Mtop   = (int*)(ws + 131072);             // 1440 (pad 2048)
    float* mean   = ws + 133120;                     // 2048 (SUM; zeroed in kTopF, scaled in kOut)
    unsigned short* selRow16 = (unsigned short*)(ws + 135168);  // 131072 u16 = 65536 floats
    float* mlG    = ws + 266240;                     // 32*16*45*2 = 46080 (pad 49152)
    float* Opart  = ws + 315392;                     // 32*16*45*64 = 1474560
    // total = 1,789,952 floats = 7.2 MB

    kM        <<<dim3(2048),       dim3(256), 0, stream>>>(Qb, Kb, idx, M);
    kTopF     <<<dim3(32),         dim3(512), 0, stream>>>(M, Mtop, mean, selRow16);
    kAttnPart <<<dim3(KC_, 32, 2), dim3(256), 0, stream>>>(Qb, Kb, Vb, Mtop, Opart, mlG, mean);
    kOut      <<<dim3(8192),       dim3(256), 0, stream>>>(mean, selRow16, mlG, Opart, out);
}

// Round 12
// 276.798 us; speedup vs baseline: 1.2084x; 1.1105x over previous
//
#include <hip/hip_runtime.h>
#include <stdint.h>

#define B_ 4
#define L_ 4096
#define H_ 8
#define D_ 64
#define S_ 45
#define U_ 45
#define BH_ 32
#define KC_ 16                     // split-k chunks (256 keys each)
#define STRIDE_ (H_*D_)            // 512 floats between consecutive l
#define BSTR_ ((size_t)L_*H_*D_)   // 2097152 floats per batch

// index_sample declared int64 in the reference; harness may pass int32 or int64.
__device__ __forceinline__ bool detect_idx64(const int* idxp){
    bool z = true;
    #pragma unroll
    for (int i = 1; i < 32; i += 2) z = z && (idxp[i] == 0);
    return z;
}

// Nontemporal float4 load/store (HIP float4 is a struct; go through ext_vector).
typedef float v4f_ __attribute__((ext_vector_type(4)));
__device__ __forceinline__ float4 ntload4(const float4* p){
    v4f_ v = __builtin_nontemporal_load((const v4f_*)p);
    return make_float4(v.x, v.y, v.z, v.w);
}
__device__ __forceinline__ void ntstore4(float4* p, float4 f){
    v4f_ v; v.x = f.x; v.y = f.y; v.z = f.z; v.w = f.w;
    __builtin_nontemporal_store(v, (v4f_*)p);
}

// ---------- kernel A: M[bh][q] = max_s(dot) - sum_s(dot)/L ----------
// R4-BEST STRUCTURE — DECLARED FLOOR. 4-head-fused gather: one sample row =
// K[b, ki, hg*4..+3, :] = 1 KB contiguous; 16-lane group per q gives 4
// independent gather streams per wave instr (R10's wave-per-sample serial
// variant regressed 77->98). One (b,hg) per XCD via g&7 -> 4.0 MB hot K slice
// (8 MB thrashes, R5). FETCH == compulsory; 77 us = 2.45 TB/s/XCD ~ 57% of L2
// streaming rate = random-channel queuing asymptote.
__global__ __launch_bounds__(256) void kM(const float* __restrict__ Qb,
                                          const float* __restrict__ Kb,
                                          const int* __restrict__ idxp,
                                          float* __restrict__ Mout){
    int g = blockIdx.x;                 // 0..2047
    int grp8 = g & 7;                   // one (b, head-half) per XCD
    int b  = grp8 >> 1;
    int hg = grp8 & 1;
    int chunk = g >> 3;                 // 0..255
    int q0 = chunk * 16;
    bool idx64 = detect_idx64(idxp);

    __shared__ int lidx[16*S_];         // 2.88 KB: this block's 16 q x 45 idx
    for (int i = threadIdx.x; i < 16*S_; i += 256)
        lidx[i] = idx64 ? __builtin_nontemporal_load(&idxp[2*(q0*S_ + i)])
                        : __builtin_nontemporal_load(&idxp[q0*S_ + i]);
    __syncthreads();

    int lane = threadIdx.x & 63;
    int w    = threadIdx.x >> 6;        // wave 0..3
    int grp  = lane >> 4;               // 16-lane group: one q each
    int l16  = lane & 15;
    int ql   = w*4 + grp;               // 0..15
    int q    = q0 + ql;

    const float4* qr = (const float4*)(Qb + (size_t)b*BSTR_ + (size_t)q*STRIDE_ + hg*256);
    float4 qf0 = ntload4(qr + l16);        // head hg*4+0, dims l16*4..+3
    float4 qf1 = ntload4(qr + 16 + l16);   // head hg*4+1
    float4 qf2 = ntload4(qr + 32 + l16);   // head hg*4+2
    float4 qf3 = ntload4(qr + 48 + l16);   // head hg*4+3

    const float* kbase = Kb + (size_t)b*BSTR_ + hg*256;
    // lane<8 of each group accumulates heads {0,1}; lane>=8 heads {2,3}
    float mxa = -1e30f, mxb = -1e30f, sma = 0.f, smb = 0.f;
    const int* myIdx = &lidx[ql*S_];

    #pragma unroll 3
    for (int s = 0; s < S_; s++){
        int ki = myIdx[s];              // broadcast within group
        const float4* kr = (const float4*)(kbase + (size_t)ki*STRIDE_);
        float4 k0 = kr[l16], k1 = kr[16+l16], k2 = kr[32+l16], k3 = kr[48+l16];
        float p0 = qf0.x*k0.x; p0 = fmaf(qf0.y,k0.y,p0); p0 = fmaf(qf0.z,k0.z,p0); p0 = fmaf(qf0.w,k0.w,p0);
        float p1 = qf1.x*k1.x; p1 = fmaf(qf1.y,k1.y,p1); p1 = fmaf(qf1.z,k1.z,p1); p1 = fmaf(qf1.w,k1.w,p1);
        float p2 = qf2.x*k2.x; p2 = fmaf(qf2.y,k2.y,p2); p2 = fmaf(qf2.z,k2.z,p2); p2 = fmaf(qf2.w,k2.w,p2);
        float p3 = qf3.x*k3.x; p3 = fmaf(qf3.y,k3.y,p3); p3 = fmaf(qf3.z,k3.z,p3); p3 = fmaf(qf3.w,k3.w,p3);
        // fold the two 8-lane halves of each head partial (1 shfl each)
        float u0 = p0 + __shfl_xor(p0, 8);
        float u1 = p1 + __shfl_xor(p1, 8);
        float u2 = p2 + __shfl_xor(p2, 8);
        float u3 = p3 + __shfl_xor(p3, 8);
        // lane specialization: low half carries heads 0/1, high half 2/3
        float va = (l16 < 8) ? u0 : u2;
        float vb = (l16 < 8) ? u1 : u3;
        #pragma unroll
        for (int off = 1; off < 8; off <<= 1){
            va += __shfl_xor(va, off);
            vb += __shfl_xor(vb, off);
        }
        mxa = fmaxf(mxa, va); sma += va;
        mxb = fmaxf(mxb, vb); smb += vb;
    }
    // writers: l16==0 -> head0(a), l16==1 -> head1(b), l16==8 -> head2(a), l16==9 -> head3(b)
    int hsel = (l16==0) ? 0 : (l16==1) ? 1 : (l16==8) ? 2 : (l16==9) ? 3 : -1;
    if (hsel >= 0){
        float mv = (l16 & 1) ? mxb : mxa;
        float sv = (l16 & 1) ? smb : sma;
        __builtin_nontemporal_store(mv - sv*(1.0f/L_),
            &Mout[(size_t)(b*8 + hg*4 + hsel)*L_ + q]);
    }
}

// ---------- top-k phase A: per-segment top-45 (256 blocks, 1 wave each) ----------
// R11 finding: the old single-kernel kTopF was 79 us at 1.5% occupancy /
// 2.2% VALU — 32 blocks on 256 CUs running ~90 serial butterfly rounds.
// Phase A spreads the 45-round extraction over 256 concurrent waves (one per
// (bh, 512-value segment)); emits lists SORTED by (v desc, idx asc).
__global__ __launch_bounds__(64) void kTopSeg(const float* __restrict__ M,
                                              float* __restrict__ candV,
                                              int*   __restrict__ candI,
                                              unsigned short* __restrict__ selRow16){
    int g = blockIdx.x;                // 0..255
    int bh = g >> 3, seg = g & 7;
    int lane = threadIdx.x;            // 0..63
    // zero this (bh,seg) slice of selRow16: 512 u16 = 1 KB, 16 B per lane
    uint4 z; z.x = z.y = z.z = z.w = 0u;
    ((uint4*)(selRow16 + (size_t)bh*L_ + seg*512))[lane] = z;

    const float* Mr = M + (size_t)bh*L_ + seg*512;
    float v[8];
    #pragma unroll
    for (int j = 0; j < 8; j++) v[j] = Mr[lane + 64*j];

    float* cV = candV + (size_t)g*U_;
    int*   cI = candI + (size_t)g*U_;
    for (int it = 0; it < U_; it++){
        float best = -1e30f; int bidx = 0x7fffffff;
        #pragma unroll
        for (int j = 0; j < 8; j++){
            int id = lane + 64*j;
            if (v[j] > best){ best = v[j]; bidx = id; }   // ascending id scan
        }
        #pragma unroll
        for (int off = 1; off < 64; off <<= 1){
            float ov = __shfl_xor(best, off); int oi = __shfl_xor(bidx, off);
            if (ov > best || (ov == best && oi < bidx)){ best = ov; bidx = oi; }
        }
        if (lane == 0){ cV[it] = best; cI[it] = seg*512 + bidx; }
        if (lane == (bidx & 63)) v[bidx >> 6] = -1e30f;
    }
}

// ---------- top-k phase B: parallel rank-merge of 8 sorted lists ----------
// Each of the 360 candidates computes its global rank = own-list rank +
// sum over the 7 other sorted lists of lower_bound position (6-step binary
// search, lexicographic (v desc, idx asc) == jax.lax.top_k tie order).
// rank < 45 -> Mtop[rank], selRow16 = rank+1. No serial extraction rounds.
__global__ __launch_bounds__(384) void kTopMerge(const float* __restrict__ candV,
                                                 const int*   __restrict__ candI,
                                                 int* __restrict__ Mtop,
                                                 unsigned short* __restrict__ selRow16,
                                                 float* __restrict__ meanZ){
    int bh = blockIdx.x;
    int t = threadIdx.x;
    if (t < 64) meanZ[bh*64 + t] = 0.f;
    __shared__ float sV[8*U_];
    __shared__ int   sI[8*U_];
    if (t < 8*U_){ sV[t] = candV[(size_t)bh*8*U_ + t]; sI[t] = candI[(size_t)bh*8*U_ + t]; }
    __syncthreads();
    if (t < 8*U_){
        int s = t / U_, r = t - s*U_;
        float v = sV[t]; int gi = sI[t];
        int rank = r;
        for (int s2 = 0; s2 < 8; s2++){
            if (s2 == s) continue;
            const float* LV = &sV[s2*U_];
            const int*   LI = &sI[s2*U_];
            int lo = 0, hi = U_;
            while (lo < hi){
                int mid = (lo + hi) >> 1;
                bool before = (LV[mid] > v) || (LV[mid] == v && LI[mid] < gi);
                if (before) lo = mid + 1; else hi = mid;
            }
            rank += lo;
        }
        if (rank < U_){
            Mtop[bh*U_ + rank] = gi;
            selRow16[(size_t)bh*L_ + gi] = (unsigned short)(rank + 1);
        }
    }
}

// ---------- fused flash split-k+u: scores + softmax partials + PV + V-sum ----------
// R8-BEST config — UNTOUCHED (uh=2, 1024 blocks, ~25 KB LDS; Q via
// readfirstlane scalar loads). Phase 3 d-major shuffle-free.
__global__ __launch_bounds__(256) void kAttnPart(const float* __restrict__ Qb,
                                                 const float* __restrict__ Kb,
                                                 const float* __restrict__ Vb,
                                                 const int*   __restrict__ Mtop,
                                                 float* __restrict__ Opart,
                                                 float* __restrict__ mlG,
                                                 float* __restrict__ mean){
    int bh = blockIdx.y, b = bh >> 3, h = bh & 7;
    int kc = blockIdx.x, uh = blockIdx.z;
    int u0 = uh ? 23 : 0;
    int nu = uh ? 22 : 23;
    int t = threadIdx.x;
    __shared__ float S[24][260];          // 24.4 KB (rows >= nu zeroed scratch)
    __shared__ int   qidx[23];

    if (t < nu) qidx[t] = Mtop[bh*U_ + u0 + t];
    // zero scratch rows nu..23 so phase-3 over-read rows contribute 0 (no NaN)
    for (int i = t; i < (24 - nu)*260; i += 256) (&S[nu][0])[i] = 0.f;
    __syncthreads();

    // Phase 1: scores for this block's 256 keys, its nu queries.
    int k = kc*256 + t;
    float4 kf[16];
    const float4* K4 = (const float4*)(Kb + (size_t)b*BSTR_ + (size_t)k*STRIDE_ + h*D_);
    #pragma unroll
    for (int c = 0; c < 16; c++) kf[c] = K4[c];
    for (int u = 0; u < nu; u++){
        int qi = __builtin_amdgcn_readfirstlane(qidx[u]);   // wave-uniform -> scalar loads
        const float4* qp = (const float4*)(Qb + (size_t)b*BSTR_ + (size_t)qi*STRIDE_ + h*D_);
        float a0=0.f, a1=0.f, a2=0.f, a3=0.f;
        #pragma unroll
        for (int c = 0; c < 16; c++){
            float4 qv = qp[c];
            a0 = fmaf(qv.x, kf[c].x, a0);
            a1 = fmaf(qv.y, kf[c].y, a1);
            a2 = fmaf(qv.z, kf[c].z, a2);
            a3 = fmaf(qv.w, kf[c].w, a3);
        }
        S[u][t] = ((a0+a1)+(a2+a3)) * 0.125f;
    }
    __syncthreads();

    // Phase 2: per-u softmax partial over 256 scores (one wave per u).
    int wv = t >> 6, lane = t & 63;
    for (int u = wv; u < nu; u += 4){
        float4 sv = *(const float4*)&S[u][lane*4];
        float m = fmaxf(fmaxf(sv.x, sv.y), fmaxf(sv.z, sv.w));
        #pragma unroll
        for (int off = 1; off < 64; off <<= 1) m = fmaxf(m, __shfl_xor(m, off));
        float e0 = __expf(sv.x - m), e1 = __expf(sv.y - m);
        float e2 = __expf(sv.z - m), e3 = __expf(sv.w - m);
        float ls = (e0+e1)+(e2+e3);
        #pragma unroll
        for (int off = 1; off < 64; off <<= 1) ls += __shfl_xor(ls, off);
        float4 pv; pv.x = e0; pv.y = e1; pv.z = e2; pv.w = e3;
        *(float4*)&S[u][lane*4] = pv;
        if (lane == 0){
            size_t mi = ((size_t)(bh*KC_ + kc)*U_ + u0 + u)*2;
            mlG[mi] = m; mlG[mi+1] = ls;
        }
    }
    __syncthreads();

    // Phase 3: d-major, shuffle-free. lane d owns output column d;
    // wave w owns u rows [w*6, w*6+6). k-reduction thread-local.
    int d = lane, w = wv;
    int ub = w*6;
    int nuw = nu - ub; if (nuw > 6) nuw = 6; if (nuw < 0) nuw = 0;
    float acc[6];
    #pragma unroll
    for (int j = 0; j < 6; j++) acc[j] = 0.f;
    float vsum = 0.f;
    const float* Vbase = Vb + (size_t)b*BSTR_ + (size_t)(kc*256)*STRIDE_ + h*D_ + d;
    for (int kb = 0; kb < 64; kb++){
        // V[k][d] for 4 consecutive k: wave-coalesced 256 B row reads
        float v0 = Vbase[(size_t)(kb*4+0)*STRIDE_];
        float v1 = Vbase[(size_t)(kb*4+1)*STRIDE_];
        float v2 = Vbase[(size_t)(kb*4+2)*STRIDE_];
        float v3 = Vbase[(size_t)(kb*4+3)*STRIDE_];
        if (uh == 0 && w == 0) vsum += (v0+v1)+(v2+v3);
        #pragma unroll
        for (int j = 0; j < 6; j++){
            float4 p = *(const float4*)&S[ub+j][kb*4];   // wave-uniform broadcast
            acc[j] = fmaf(p.x, v0, acc[j]);
            acc[j] = fmaf(p.y, v1, acc[j]);
            acc[j] = fmaf(p.z, v2, acc[j]);
            acc[j] = fmaf(p.w, v3, acc[j]);
        }
    }
    for (int j = 0; j < nuw; j++)
        Opart[((size_t)(bh*KC_ + kc)*U_ + u0 + ub + j)*64 + d] = acc[j];
    // V column-sum -> mean (SUM). Only uh==0, wave 0 contributes.
    if (uh == 0 && w == 0)
        atomicAdd(&mean[bh*64 + d], vsum);
}

// ---------- fused output: mean fill + inline split-k merge (one kernel) ----------
__global__ __launch_bounds__(256) void kOut(const float* __restrict__ mean,
                                            const unsigned short* __restrict__ selRow16,
                                            const float* __restrict__ mlG,
                                            const float* __restrict__ Opart,
                                            float* __restrict__ out){
    size_t t = (size_t)blockIdx.x*256 + threadIdx.x;   // one float4; 2,097,152 total
    int d16 = (int)(t & 15); int h = (int)((t >> 4) & 7);
    int l   = (int)((t >> 7) & 4095); int b = (int)(t >> 19);
    int bh = b*8 + h;
    int sel = selRow16[(size_t)bh*L_ + l];
    float4 o;
    if (sel == 0){
        o = *(const float4*)(mean + bh*64 + d16*4);
        const float inv = 1.0f / L_;
        o.x *= inv; o.y *= inv; o.z *= inv; o.w *= inv;
    } else {
        int u = sel - 1;
        float mstar = -1e30f;
        #pragma unroll
        for (int kc = 0; kc < KC_; kc++)
            mstar = fmaxf(mstar, mlG[((size_t)(bh*KC_ + kc)*U_ + u)*2]);
        float lsum = 0.f;
        float4 acc; acc.x = acc.y = acc.z = acc.w = 0.f;
        #pragma unroll
        for (int kc = 0; kc < KC_; kc++){
            size_t mi = ((size_t)(bh*KC_ + kc)*U_ + u)*2;
            float wgt = __expf(mlG[mi] - mstar);
            lsum = fmaf(mlG[mi+1], wgt, lsum);
            float4 op = *(const float4*)(Opart + ((size_t)(bh*KC_ + kc)*U_ + u)*64 + d16*4);
            acc.x = fmaf(wgt, op.x, acc.x);
            acc.y = fmaf(wgt, op.y, acc.y);
            acc.z = fmaf(wgt, op.z, acc.z);
            acc.w = fmaf(wgt, op.w, acc.w);
        }
        float inv = 1.0f / lsum;
        acc.x *= inv; acc.y *= inv; acc.z *= inv; acc.w *= inv;
        o = acc;
    }
    ntstore4(((float4*)out) + t, o);
}

extern "C" void kernel_launch(void* const* d_in, const int* in_sizes, int n_in,
                              void* d_out, int out_size, void* d_ws, size_t ws_size,
                              hipStream_t stream) {
    const float* Qb  = (const float*)d_in[0];
    const float* Kb  = (const float*)d_in[1];
    const float* Vb  = (const float*)d_in[2];
    const int*   idx = (const int*)d_in[3];
    float* out = (float*)d_out;

    float* ws = (float*)d_ws;
    // ws layout (float offsets)
    float* M      = ws;                              // 131072
    int*   Mtop   = (int*)(ws + 131072);             // 1440 (pad 2048)
    float* mean   = ws + 133120;                     // 2048 (SUM; zeroed in kTopMerge, scaled in kOut)
    unsigned short* selRow16 = (unsigned short*)(ws + 135168);  // 131072 u16 = 65536 floats
    float* candV  = ws + 200704;                     // 256*45 = 11520
    int*   candI  = (int*)(ws + 212224);             // 11520 (ends 223744 < 266240)
    float* mlG    = ws + 266240;                     // 32*16*45*2 = 46080 (pad 49152)
    float* Opart  = ws + 315392;                     // 32*16*45*64 = 1474560
    // total = 1,789,952 floats = 7.2 MB

    kM        <<<dim3(2048),       dim3(256), 0, stream>>>(Qb, Kb, idx, M);
    kTopSeg   <<<dim3(256),        dim3(64),  0, stream>>>(M, candV, candI, selRow16);
    kTopMerge <<<dim3(32),         dim3(384), 0, stream>>>(candV, candI, Mtop, selRow16, mean);
    kAttnPart <<<dim3(KC_, 32, 2), dim3(256), 0, stream>>>(Qb, Kb, Vb, Mtop, Opart, mlG, mean);
    kOut      <<<dim3(8192),       dim3(256), 0, stream>>>(mean, selRow16, mlG, Opart, out);
}